// Round 1
// baseline (583.195 us; speedup 1.0000x reference)
//
#include <hip/hip_runtime.h>
#include <hip/hip_bf16.h>

typedef float f32x4 __attribute__((ext_vector_type(4)));
typedef __bf16 bf16x8 __attribute__((ext_vector_type(8)));
typedef unsigned short ushort_t;
typedef ushort_t u16x8 __attribute__((ext_vector_type(8)));

#define GLDS16(gp, lp)                                                        \
  __builtin_amdgcn_global_load_lds(                                           \
      (__attribute__((address_space(1))) void*)(gp),                          \
      (__attribute__((address_space(3))) void*)(lp), 16, 0, 0)

__device__ __forceinline__ ushort_t f2bf(float f) {
  unsigned u = __float_as_uint(f);
  unsigned r = u + 0x7fffu + ((u >> 16) & 1u);  // round-to-nearest-even
  return (ushort_t)(r >> 16);
}

__device__ __forceinline__ int swz(int row) {
  return (row & 3) ^ ((row >> 2) & 3);
}

// ---------------------------------------------------------------------------
// W1 [K=1024][N=1024] fp32 -> w1t [N][K] bf16 (transpose + convert)
// ---------------------------------------------------------------------------
__global__ __launch_bounds__(256) void prep_w1(const float* __restrict__ w1,
                                               ushort_t* __restrict__ w1t) {
  __shared__ ushort_t tile[64][80];
  const int k0 = blockIdx.x * 64;
  const int n0 = blockIdx.y * 64;
  const int tid = threadIdx.x;
#pragma unroll
  for (int it = 0; it < 16; ++it) {
    int idx = it * 256 + tid;
    int k = idx >> 6, n = idx & 63;
    tile[n][k] = f2bf(w1[(size_t)(k0 + k) * 1024 + n0 + n]);
  }
  __syncthreads();
#pragma unroll
  for (int it = 0; it < 2; ++it) {
    int idx = it * 256 + tid;
    int n = idx >> 3, kk = (idx & 7) * 8;
    bf16x8 v = *(const bf16x8*)&tile[n][kk];
    *(bf16x8*)&w1t[(size_t)(n0 + n) * 1024 + k0 + kk] = v;
  }
}

// ---------------------------------------------------------------------------
// x fp32 [64M] -> xbf bf16 row-major [65536][1024]
// ---------------------------------------------------------------------------
__global__ __launch_bounds__(256) void prep_x(const float* __restrict__ x,
                                              ushort_t* __restrict__ xbf) {
  size_t i = ((size_t)blockIdx.x * 256 + threadIdx.x) * 8;
  float4 a = *(const float4*)(x + i);
  float4 b = *(const float4*)(x + i + 4);
  u16x8 o;
  o[0] = f2bf(a.x); o[1] = f2bf(a.y); o[2] = f2bf(a.z); o[3] = f2bf(a.w);
  o[4] = f2bf(b.x); o[5] = f2bf(b.y); o[6] = f2bf(b.z); o[7] = f2bf(b.w);
  *(u16x8*)(xbf + i) = o;
}

// ---------------------------------------------------------------------------
// Fused: 128-row strip GEMM (BN=256 per n-iter, 4 iters) -> logits in LDS ->
// softmax over each 2x2 window -> weighted sum of fp32 x rows -> out.
// K-loop is now a pipelined double-buffer: stage tile t+1 (global_load_lds,
// no wait) BEFORE computing tile t; single __syncthreads per kt (the vmcnt(0)
// drain now lands AFTER ~32 MFMAs of overlap instead of immediately).
// ---------------------------------------------------------------------------
#define FOLD_EPILOGUE(ACC, NH)                                                \
  {                                                                           \
    float bv[4], wv[4];                                                       \
    _Pragma("unroll") for (int ni = 0; ni < 4; ++ni) {                        \
      int col = nt * 256 + (NH)*128 + wn + ni * 16 + lc;                      \
      bv[ni] = b1[col];                                                       \
      wv[ni] = w2[col];                                                       \
    }                                                                         \
    _Pragma("unroll") for (int mi = 0; mi < 4; ++mi)                          \
        _Pragma("unroll") for (int r = 0; r < 4; ++r) {                       \
      float s = 0.f;                                                          \
      _Pragma("unroll") for (int ni = 0; ni < 4; ++ni) {                      \
        float h = ACC[mi][ni][r] + bv[ni];                                    \
        h = h > 0.f ? h : 0.f;                                                \
        s += h * wv[ni];                                                      \
      }                                                                       \
      racc[mi][r] += s;                                                       \
    }                                                                         \
  }

template <bool A_BF16>
__global__ __launch_bounds__(256, 2) void gemm_fused(
    const void* __restrict__ aglob, const ushort_t* __restrict__ w1t,
    const float* __restrict__ b1, const float* __restrict__ w2,
    const float* __restrict__ x, float* __restrict__ out) {
  __shared__ ushort_t As[2][128 * 32];   // 16 KB
  __shared__ ushort_t Bs0[2][128 * 32];  // 16 KB
  __shared__ ushort_t Bs1[2][128 * 32];  // 16 KB
  __shared__ float lbuf[128];
  __shared__ float abuf[128];  // alpha[j*4+k]

  const int tid = threadIdx.x;
  const int wave = tid >> 6, lane = tid & 63;
  const int quad = lane >> 4, lc = lane & 15;
  const int m0 = blockIdx.x * 128;
  const int wm = (wave & 1) * 64, wn = (wave >> 1) * 64;

  // Staging: thread covers LDS chunks g0/g1 (16 B each); source chunk swizzled
  const int g0 = tid, g1 = 256 + tid;
  const int r0 = g0 >> 2, c0 = (g0 & 3) ^ swz(g0 >> 2);
  const int r1 = g1 >> 2, c1 = (g1 & 3) ^ swz(g1 >> 2);
  const ushort_t* abf0 = nullptr; const ushort_t* abf1 = nullptr;
  const float* af0 = nullptr; const float* af1 = nullptr;
  if constexpr (A_BF16) {
    abf0 = (const ushort_t*)aglob + (size_t)(m0 + r0) * 1024 + c0 * 8;
    abf1 = (const ushort_t*)aglob + (size_t)(m0 + r1) * 1024 + c1 * 8;
  } else {
    af0 = (const float*)aglob + (size_t)(m0 + r0) * 1024 + c0 * 8;
    af1 = (const float*)aglob + (size_t)(m0 + r1) * 1024 + c1 * 8;
  }
  const ushort_t* b00 = w1t + (size_t)r0 * 1024 + c0 * 8;         // Bs0 tile
  const ushort_t* b01 = w1t + (size_t)r1 * 1024 + c1 * 8;
  const ushort_t* b10 = w1t + (size_t)(128 + r0) * 1024 + c0 * 8; // Bs1 tile
  const ushort_t* b11 = w1t + (size_t)(128 + r1) * 1024 + c1 * 8;

  int aoff[4], boff[4];
#pragma unroll
  for (int mi = 0; mi < 4; ++mi) {
    int r = wm + mi * 16 + lc;
    aoff[mi] = r * 32 + (quad ^ swz(r)) * 8;
  }
#pragma unroll
  for (int ni = 0; ni < 4; ++ni) {
    int r = wn + ni * 16 + lc;
    boff[ni] = r * 32 + (quad ^ swz(r)) * 8;
  }

  // Stage tile (nt_, kt_) into buffer `buf` (issue-only for bf16 path).
  auto stage = [&](int buf, int nt_, int kt_) {
    const size_t cb = (size_t)nt_ * (256 * 1024);
    const int k0 = kt_ * 32;
    GLDS16(b00 + cb + k0, &Bs0[buf][g0 * 8]);
    GLDS16(b01 + cb + k0, &Bs0[buf][g1 * 8]);
    GLDS16(b10 + cb + k0, &Bs1[buf][g0 * 8]);
    GLDS16(b11 + cb + k0, &Bs1[buf][g1 * 8]);
    if constexpr (A_BF16) {
      GLDS16(abf0 + k0, &As[buf][g0 * 8]);
      GLDS16(abf1 + k0, &As[buf][g1 * 8]);
    } else {
      const int k0f = kt_ * 32;
      float4 v0 = *(const float4*)(af0 + k0f);
      float4 v1 = *(const float4*)(af0 + k0f + 4);
      float4 v2 = *(const float4*)(af1 + k0f);
      float4 v3 = *(const float4*)(af1 + k0f + 4);
      u16x8 o0, o1;
      o0[0] = f2bf(v0.x); o0[1] = f2bf(v0.y); o0[2] = f2bf(v0.z); o0[3] = f2bf(v0.w);
      o0[4] = f2bf(v1.x); o0[5] = f2bf(v1.y); o0[6] = f2bf(v1.z); o0[7] = f2bf(v1.w);
      o1[0] = f2bf(v2.x); o1[1] = f2bf(v2.y); o1[2] = f2bf(v2.z); o1[3] = f2bf(v2.w);
      o1[4] = f2bf(v3.x); o1[5] = f2bf(v3.y); o1[6] = f2bf(v3.z); o1[7] = f2bf(v3.w);
      *(u16x8*)&As[buf][g0 * 8] = o0;
      *(u16x8*)&As[buf][g1 * 8] = o1;
    }
  };

  float racc[4][4] = {};

  // Pipeline prologue: tile (0,0) into buffer 0, drain, barrier.
  stage(0, 0, 0);
  __syncthreads();

  for (int nt = 0; nt < 4; ++nt) {
    f32x4 acc0[4][4] = {};
    f32x4 acc1[4][4] = {};
#pragma unroll 2
    for (int kt = 0; kt < 32; ++kt) {
      const int cur = kt & 1;
      // Prefetch next tile (crosses the nt boundary to keep pipeline full).
      if (!(nt == 3 && kt == 31)) {
        int nk = kt + 1, nn = nt;
        if (nk == 32) { nk = 0; nn = nt + 1; }
        stage(cur ^ 1, nn, nk);
      }

      bf16x8 afr[4], bfr0[4], bfr1[4];
#pragma unroll
      for (int mi = 0; mi < 4; ++mi) afr[mi] = *(const bf16x8*)&As[cur][aoff[mi]];
#pragma unroll
      for (int ni = 0; ni < 4; ++ni) {
        bfr0[ni] = *(const bf16x8*)&Bs0[cur][boff[ni]];
        bfr1[ni] = *(const bf16x8*)&Bs1[cur][boff[ni]];
      }
#pragma unroll
      for (int mi = 0; mi < 4; ++mi)
#pragma unroll
        for (int ni = 0; ni < 4; ++ni) {
          acc0[mi][ni] = __builtin_amdgcn_mfma_f32_16x16x32_bf16(
              afr[mi], bfr0[ni], acc0[mi][ni], 0, 0, 0);
          acc1[mi][ni] = __builtin_amdgcn_mfma_f32_16x16x32_bf16(
              afr[mi], bfr1[ni], acc1[mi][ni], 0, 0, 0);
        }
      // One barrier per kt: drains this iter's prefetch (overlapped with the
      // MFMAs above) and publishes buffer cur^1 for the next iteration.
      __syncthreads();
    }
    FOLD_EPILOGUE(acc0, 0)
    FOLD_EPILOGUE(acc1, 1)
  }

  // Reduce racc over the 16 columns per lane-group -> per-row logits in LDS.
#pragma unroll
  for (int mi = 0; mi < 4; ++mi)
#pragma unroll
    for (int r = 0; r < 4; ++r)
#pragma unroll
      for (int off = 1; off < 16; off <<= 1)
        racc[mi][r] += __shfl_xor(racc[mi][r], off, 64);
  __syncthreads();
  if (tid < 128) lbuf[tid] = 0.f;
  __syncthreads();
  if (lc == 0) {
#pragma unroll
    for (int mi = 0; mi < 4; ++mi)
#pragma unroll
      for (int r = 0; r < 4; ++r)
        atomicAdd(&lbuf[wm + mi * 16 + quad * 4 + r], racc[mi][r]);
  }
  __syncthreads();

  // Softmax per 2x2 window (b2 omitted: shift-invariant).
  if (tid < 32) {
    const int j = tid;
    float l0 = lbuf[2 * j], l1 = lbuf[2 * j + 1];
    float l2 = lbuf[64 + 2 * j], l3 = lbuf[65 + 2 * j];
    float mx = fmaxf(fmaxf(l0, l1), fmaxf(l2, l3));
    float e0 = __expf(l0 - mx), e1 = __expf(l1 - mx);
    float e2 = __expf(l2 - mx), e3 = __expf(l3 - mx);
    float inv = 1.0f / (e0 + e1 + e2 + e3);
    abuf[j * 4 + 0] = e0 * inv;
    abuf[j * 4 + 1] = e1 * inv;
    abuf[j * 4 + 2] = e2 * inv;
    abuf[j * 4 + 3] = e3 * inv;
  }
  __syncthreads();

  // Weighted sum: out row b*1024 + i*32 + j  (block = b*32 + i).
  const int b = blockIdx.x >> 5, ii = blockIdx.x & 31;
  const float* xs = x + (size_t)m0 * 1024;
  float* orow = out + ((size_t)(b * 1024 + ii * 32)) * 1024;
  for (int j = 0; j < 32; ++j) {
    float a0 = abuf[j * 4 + 0], a1 = abuf[j * 4 + 1];
    float a2 = abuf[j * 4 + 2], a3 = abuf[j * 4 + 3];
    const float4* p0 = (const float4*)(xs + (size_t)(2 * j) * 1024);
    const float4* p1 = (const float4*)(xs + (size_t)(2 * j + 1) * 1024);
    const float4* p2 = (const float4*)(xs + (size_t)(64 + 2 * j) * 1024);
    const float4* p3 = (const float4*)(xs + (size_t)(65 + 2 * j) * 1024);
    float4 v0 = p0[tid], v1 = p1[tid], v2 = p2[tid], v3 = p3[tid];
    float4 o;
    o.x = a0 * v0.x + a1 * v1.x + a2 * v2.x + a3 * v3.x;
    o.y = a0 * v0.y + a1 * v1.y + a2 * v2.y + a3 * v3.y;
    o.z = a0 * v0.z + a1 * v1.z + a2 * v2.z + a3 * v3.z;
    o.w = a0 * v0.w + a1 * v1.w + a2 * v2.w + a3 * v3.w;
    ((float4*)(orow + (size_t)j * 1024))[tid] = o;
  }
}

// ---------------------------------------------------------------------------
extern "C" void kernel_launch(void* const* d_in, const int* in_sizes, int n_in,
                              void* d_out, int out_size, void* d_ws,
                              size_t ws_size, hipStream_t stream) {
  const float* x  = (const float*)d_in[0];  // [16, 4096, 1024]
  const float* W1 = (const float*)d_in[1];  // [1024, 1024]
  const float* b1 = (const float*)d_in[2];  // [1024]
  const float* W2 = (const float*)d_in[3];  // [1024, 1]
  float* out = (float*)d_out;               // [16, 1024, 1024]

  const size_t XBF_BYTES = 134217728ull;  // 64M bf16
  const size_t W1T_BYTES = 2097152ull;

  if (ws_size >= XBF_BYTES + W1T_BYTES) {
    ushort_t* xbf = (ushort_t*)d_ws;
    ushort_t* w1t = (ushort_t*)((char*)d_ws + XBF_BYTES);
    prep_x<<<32768, 256, 0, stream>>>(x, xbf);
    prep_w1<<<dim3(16, 16), 256, 0, stream>>>(W1, w1t);
    gemm_fused<true><<<512, 256, 0, stream>>>(xbf, w1t, b1, W2, x, out);
  } else {
    ushort_t* w1t = (ushort_t*)d_ws;
    prep_w1<<<dim3(16, 16), 256, 0, stream>>>(W1, w1t);
    gemm_fused<false><<<512, 256, 0, stream>>>(x, w1t, b1, W2, x, out);
  }
}

// Round 2
// 581.191 us; speedup vs baseline: 1.0034x; 1.0034x over previous
//
#include <hip/hip_runtime.h>
#include <hip/hip_bf16.h>

typedef float f32x4 __attribute__((ext_vector_type(4)));
typedef __bf16 bf16x8 __attribute__((ext_vector_type(8)));
typedef unsigned short ushort_t;
typedef ushort_t u16x8 __attribute__((ext_vector_type(8)));

#define GLDS16(gp, lp)                                                        \
  __builtin_amdgcn_global_load_lds(                                           \
      (__attribute__((address_space(1))) void*)(gp),                          \
      (__attribute__((address_space(3))) void*)(lp), 16, 0, 0)

__device__ __forceinline__ ushort_t f2bf(float f) {
  unsigned u = __float_as_uint(f);
  unsigned r = u + 0x7fffu + ((u >> 16) & 1u);  // round-to-nearest-even
  return (ushort_t)(r >> 16);
}

__device__ __forceinline__ int swz(int row) {
  return (row & 3) ^ ((row >> 2) & 3);
}

// ---------------------------------------------------------------------------
// W1 [K=1024][N=1024] fp32 -> w1t [N][K] bf16 (transpose + convert)
// ---------------------------------------------------------------------------
__global__ __launch_bounds__(256) void prep_w1(const float* __restrict__ w1,
                                               ushort_t* __restrict__ w1t) {
  __shared__ ushort_t tile[64][80];
  const int k0 = blockIdx.x * 64;
  const int n0 = blockIdx.y * 64;
  const int tid = threadIdx.x;
#pragma unroll
  for (int it = 0; it < 16; ++it) {
    int idx = it * 256 + tid;
    int k = idx >> 6, n = idx & 63;
    tile[n][k] = f2bf(w1[(size_t)(k0 + k) * 1024 + n0 + n]);
  }
  __syncthreads();
#pragma unroll
  for (int it = 0; it < 2; ++it) {
    int idx = it * 256 + tid;
    int n = idx >> 3, kk = (idx & 7) * 8;
    bf16x8 v = *(const bf16x8*)&tile[n][kk];
    *(bf16x8*)&w1t[(size_t)(n0 + n) * 1024 + k0 + kk] = v;
  }
}

// ---------------------------------------------------------------------------
// x fp32 [64M] -> xbf bf16 row-major [65536][1024]
// ---------------------------------------------------------------------------
__global__ __launch_bounds__(256) void prep_x(const float* __restrict__ x,
                                              ushort_t* __restrict__ xbf) {
  size_t i = ((size_t)blockIdx.x * 256 + threadIdx.x) * 8;
  float4 a = *(const float4*)(x + i);
  float4 b = *(const float4*)(x + i + 4);
  u16x8 o;
  o[0] = f2bf(a.x); o[1] = f2bf(a.y); o[2] = f2bf(a.z); o[3] = f2bf(a.w);
  o[4] = f2bf(b.x); o[5] = f2bf(b.y); o[6] = f2bf(b.z); o[7] = f2bf(b.w);
  *(u16x8*)(xbf + i) = o;
}

// ---------------------------------------------------------------------------
// Fused kernel, now 512 threads / 8 waves per block (2 blocks/CU = 16
// waves/CU = 4 waves/SIMD, up from 2). Tile 128(M) x 256(N per nt-pass),
// BK=32, double-buffered pipelined K-loop (stage t+1 before computing t,
// one __syncthreads per kt). Wave (2M x 4N grid) owns a 64x64 sub-tile.
// ---------------------------------------------------------------------------
#define FOLD_EPILOGUE(ACC)                                                    \
  {                                                                           \
    float bv[4], wv[4];                                                       \
    _Pragma("unroll") for (int ni = 0; ni < 4; ++ni) {                        \
      int col = nt * 256 + wn + ni * 16 + lc;                                 \
      bv[ni] = b1[col];                                                       \
      wv[ni] = w2[col];                                                       \
    }                                                                         \
    _Pragma("unroll") for (int mi = 0; mi < 4; ++mi)                          \
        _Pragma("unroll") for (int r = 0; r < 4; ++r) {                       \
      float s = 0.f;                                                          \
      _Pragma("unroll") for (int ni = 0; ni < 4; ++ni) {                      \
        float h = ACC[mi][ni][r] + bv[ni];                                    \
        h = h > 0.f ? h : 0.f;                                                \
        s += h * wv[ni];                                                      \
      }                                                                       \
      racc[mi][r] += s;                                                       \
    }                                                                         \
  }

template <bool A_BF16>
__global__ __launch_bounds__(512, 4) void gemm_fused(
    const void* __restrict__ aglob, const ushort_t* __restrict__ w1t,
    const float* __restrict__ b1, const float* __restrict__ w2,
    const float* __restrict__ x, float* __restrict__ out) {
  __shared__ ushort_t As[2][128 * 32];  // 16 KB
  __shared__ ushort_t Bs[2][256 * 32];  // 32 KB
  __shared__ float lbuf[128];
  __shared__ float abuf[128];  // alpha[j*4+k]

  const int tid = threadIdx.x;
  const int wave = tid >> 6, lane = tid & 63;
  const int quad = lane >> 4, lc = lane & 15;
  const int m0 = blockIdx.x * 128;
  const int wm = (wave & 1) * 64, wn = (wave >> 1) * 64;

  // Staging geometry: A tile 128x32 bf16 = 8 KB = 512 x 16B chunks (1/thread);
  // B tile 256x32 bf16 = 16 KB = 1024 chunks (2/thread). Source column-chunk
  // swizzled so readers' quad^swz(row) lookup lands on the right data.
  const int rA = tid >> 2, cA = (tid & 3) ^ swz(tid >> 2);
  const int rB0 = tid >> 2, cB0 = (tid & 3) ^ swz(rB0);
  const int rB1 = 128 + (tid >> 2), cB1 = (tid & 3) ^ swz(rB1);

  const ushort_t* abf = nullptr;
  const float* af = nullptr;
  if constexpr (A_BF16) {
    abf = (const ushort_t*)aglob + (size_t)(m0 + rA) * 1024 + cA * 8;
  } else {
    af = (const float*)aglob + (size_t)(m0 + rA) * 1024 + cA * 8;
  }
  const ushort_t* bp0 = w1t + (size_t)rB0 * 1024 + cB0 * 8;
  const ushort_t* bp1 = w1t + (size_t)rB1 * 1024 + cB1 * 8;

  int aoff[4], boff[4];
#pragma unroll
  for (int mi = 0; mi < 4; ++mi) {
    int r = wm + mi * 16 + lc;
    aoff[mi] = r * 32 + (quad ^ swz(r)) * 8;
  }
#pragma unroll
  for (int ni = 0; ni < 4; ++ni) {
    int r = wn + ni * 16 + lc;
    boff[ni] = r * 32 + (quad ^ swz(r)) * 8;
  }

  // Stage tile (nt_, kt_) into buffer `buf` (pure async issue for bf16 path).
  auto stage = [&](int buf, int nt_, int kt_) {
    const size_t cb = (size_t)nt_ * (256 * 1024);
    const int k0 = kt_ * 32;
    GLDS16(bp0 + cb + k0, &Bs[buf][tid * 8]);
    GLDS16(bp1 + cb + k0, &Bs[buf][(512 + tid) * 8]);
    if constexpr (A_BF16) {
      GLDS16(abf + k0, &As[buf][tid * 8]);
    } else {
      float4 v0 = *(const float4*)(af + k0);
      float4 v1 = *(const float4*)(af + k0 + 4);
      u16x8 o0;
      o0[0] = f2bf(v0.x); o0[1] = f2bf(v0.y); o0[2] = f2bf(v0.z); o0[3] = f2bf(v0.w);
      o0[4] = f2bf(v1.x); o0[5] = f2bf(v1.y); o0[6] = f2bf(v1.z); o0[7] = f2bf(v1.w);
      *(u16x8*)&As[buf][tid * 8] = o0;
    }
  };

  float racc[4][4] = {};

  // Pipeline prologue: tile (0,0) into buffer 0, drain, barrier.
  stage(0, 0, 0);
  __syncthreads();

  for (int nt = 0; nt < 4; ++nt) {
    f32x4 acc[4][4] = {};
#pragma unroll 2
    for (int kt = 0; kt < 32; ++kt) {
      const int cur = kt & 1;
      // Prefetch next tile (crosses the nt boundary to keep pipeline full).
      if (!(nt == 3 && kt == 31)) {
        int nk = kt + 1, nn = nt;
        if (nk == 32) { nk = 0; nn = nt + 1; }
        stage(cur ^ 1, nn, nk);
      }

      bf16x8 afr[4], bfr[4];
#pragma unroll
      for (int mi = 0; mi < 4; ++mi) afr[mi] = *(const bf16x8*)&As[cur][aoff[mi]];
#pragma unroll
      for (int ni = 0; ni < 4; ++ni) bfr[ni] = *(const bf16x8*)&Bs[cur][boff[ni]];
#pragma unroll
      for (int mi = 0; mi < 4; ++mi)
#pragma unroll
        for (int ni = 0; ni < 4; ++ni)
          acc[mi][ni] = __builtin_amdgcn_mfma_f32_16x16x32_bf16(
              afr[mi], bfr[ni], acc[mi][ni], 0, 0, 0);
      // One barrier per kt: drains this iter's prefetch (overlapped with the
      // MFMAs above) and publishes buffer cur^1 for the next iteration.
      __syncthreads();
    }
    FOLD_EPILOGUE(acc)
  }

  // Reduce racc over the 16 columns per lane-group -> per-row logits in LDS.
#pragma unroll
  for (int mi = 0; mi < 4; ++mi)
#pragma unroll
    for (int r = 0; r < 4; ++r)
#pragma unroll
      for (int off = 1; off < 16; off <<= 1)
        racc[mi][r] += __shfl_xor(racc[mi][r], off, 64);
  __syncthreads();
  if (tid < 128) lbuf[tid] = 0.f;
  __syncthreads();
  if (lc == 0) {
#pragma unroll
    for (int mi = 0; mi < 4; ++mi)
#pragma unroll
      for (int r = 0; r < 4; ++r)
        atomicAdd(&lbuf[wm + mi * 16 + quad * 4 + r], racc[mi][r]);
  }
  __syncthreads();

  // Softmax per 2x2 window (b2 omitted: shift-invariant).
  if (tid < 32) {
    const int j = tid;
    float l0 = lbuf[2 * j], l1 = lbuf[2 * j + 1];
    float l2 = lbuf[64 + 2 * j], l3 = lbuf[65 + 2 * j];
    float mx = fmaxf(fmaxf(l0, l1), fmaxf(l2, l3));
    float e0 = __expf(l0 - mx), e1 = __expf(l1 - mx);
    float e2 = __expf(l2 - mx), e3 = __expf(l3 - mx);
    float inv = 1.0f / (e0 + e1 + e2 + e3);
    abuf[j * 4 + 0] = e0 * inv;
    abuf[j * 4 + 1] = e1 * inv;
    abuf[j * 4 + 2] = e2 * inv;
    abuf[j * 4 + 3] = e3 * inv;
  }
  __syncthreads();

  // Weighted sum: out row b*1024 + i*32 + j (block = b*32 + i). 512 threads
  // process two windows (j, j+1) concurrently: jj = tid>>8, col = tid&255.
  const int b = blockIdx.x >> 5, ii = blockIdx.x & 31;
  const int jj = tid >> 8, t = tid & 255;
  const float* xs = x + (size_t)m0 * 1024;
  float* orow = out + ((size_t)(b * 1024 + ii * 32)) * 1024;
  for (int j0 = 0; j0 < 32; j0 += 2) {
    int j = j0 + jj;
    float a0 = abuf[j * 4 + 0], a1 = abuf[j * 4 + 1];
    float a2 = abuf[j * 4 + 2], a3 = abuf[j * 4 + 3];
    const float4* p0 = (const float4*)(xs + (size_t)(2 * j) * 1024);
    const float4* p1 = (const float4*)(xs + (size_t)(2 * j + 1) * 1024);
    const float4* p2 = (const float4*)(xs + (size_t)(64 + 2 * j) * 1024);
    const float4* p3 = (const float4*)(xs + (size_t)(65 + 2 * j) * 1024);
    float4 v0 = p0[t], v1 = p1[t], v2 = p2[t], v3 = p3[t];
    float4 o;
    o.x = a0 * v0.x + a1 * v1.x + a2 * v2.x + a3 * v3.x;
    o.y = a0 * v0.y + a1 * v1.y + a2 * v2.y + a3 * v3.y;
    o.z = a0 * v0.z + a1 * v1.z + a2 * v2.z + a3 * v3.z;
    o.w = a0 * v0.w + a1 * v1.w + a2 * v2.w + a3 * v3.w;
    ((float4*)(orow + (size_t)j * 1024))[t] = o;
  }
}

// ---------------------------------------------------------------------------
extern "C" void kernel_launch(void* const* d_in, const int* in_sizes, int n_in,
                              void* d_out, int out_size, void* d_ws,
                              size_t ws_size, hipStream_t stream) {
  const float* x  = (const float*)d_in[0];  // [16, 4096, 1024]
  const float* W1 = (const float*)d_in[1];  // [1024, 1024]
  const float* b1 = (const float*)d_in[2];  // [1024]
  const float* W2 = (const float*)d_in[3];  // [1024, 1]
  float* out = (float*)d_out;               // [16, 1024, 1024]

  const size_t XBF_BYTES = 134217728ull;  // 64M bf16
  const size_t W1T_BYTES = 2097152ull;

  if (ws_size >= XBF_BYTES + W1T_BYTES) {
    ushort_t* xbf = (ushort_t*)d_ws;
    ushort_t* w1t = (ushort_t*)((char*)d_ws + XBF_BYTES);
    prep_x<<<32768, 256, 0, stream>>>(x, xbf);
    prep_w1<<<dim3(16, 16), 256, 0, stream>>>(W1, w1t);
    gemm_fused<true><<<512, 512, 0, stream>>>(xbf, w1t, b1, W2, x, out);
  } else {
    ushort_t* w1t = (ushort_t*)d_ws;
    prep_w1<<<dim3(16, 16), 256, 0, stream>>>(W1, w1t);
    gemm_fused<false><<<512, 512, 0, stream>>>(x, w1t, b1, W2, x, out);
  }
}